// Round 3
// baseline (2643.270 us; speedup 1.0000x reference)
//
#include <hip/hip_runtime.h>
#include <stdint.h>

// N_NODES=500000, N_EDGES=16000000, V_DIM=2, E_DIM=3. MLP: 5->50->20->1.
//
// Strategy: per-XCD partial accumulators + XCD-L2-local atomics.
// Device-scope atomicAdd on gfx950 executes at the memory side (32B fabric
// transaction per op, ~22G ops/s ceiling -> 2.3 ms for 48M atomics). Instead,
// each XCD accumulates into its own private table using plain
// global_atomic_add_f32 (no sc1 bit -> executes in the XCD-local L2).
// Tables are indexed by the hardware XCC_ID register, so two workgroups share
// a table iff they share an L2 -> correct despite cross-XCD non-coherence.
// Node range is split into 2 passes so each XCD's live table slice (3 MB)
// stays resident in its 4 MB L2. A fused kernel reduces the 8 partials and
// applies the MLP.

#define N_XCD 8

// Real vector types (ext_vector_type) — __builtin_nontemporal_load rejects
// HIP_vector_type structs.
typedef int vi4 __attribute__((ext_vector_type(4)));
typedef float vf4 __attribute__((ext_vector_type(4)));

__device__ __forceinline__ int xcc_id() {
  int x;
  asm volatile("s_getreg_b32 %0, hwreg(HW_REG_XCC_ID)" : "=s"(x));
  return x & (N_XCD - 1);
}

// Fire-and-forget fp32 atomic with NO sc0/sc1 bits: executes in the local
// XCD's L2 (not memory-side). Cross-XCD incoherent by design (private table).
__device__ __forceinline__ void atomic_add_l2(float* p, float v) {
  asm volatile("global_atomic_add_f32 %0, %1, off"
               :
               : "v"((uint64_t)(uintptr_t)p), "v"(v)
               : "memory");
}

__global__ __launch_bounds__(256) void scatter_xcd_kernel(
    const int* __restrict__ tgt,      // edge targets, int32 [E]
    const float* __restrict__ eattr,  // [E,3]
    float* __restrict__ tables,       // [N_XCD, n_nodes, 3], pre-zeroed
    size_t table_stride,              // n_nodes*3
    int n_edges, int lo, int hi) {    // only scatter targets in [lo,hi)
  int t = blockIdx.x * blockDim.x + threadIdx.x;
  int e0 = t * 4;
  if (e0 >= n_edges) return;
  float* table = tables + (size_t)xcc_id() * table_stride;

  if (e0 + 4 <= n_edges) {
    vi4 d4 = __builtin_nontemporal_load((const vi4*)(tgt + e0));
    const vf4* ea = (const vf4*)(eattr + (size_t)e0 * 3);
    vf4 a = __builtin_nontemporal_load(ea);
    vf4 b = __builtin_nontemporal_load(ea + 1);
    vf4 c = __builtin_nontemporal_load(ea + 2);
    if (d4.x >= lo && d4.x < hi) {
      float* p = table + (size_t)d4.x * 3;
      atomic_add_l2(p + 0, a.x);
      atomic_add_l2(p + 1, a.y);
      atomic_add_l2(p + 2, a.z);
    }
    if (d4.y >= lo && d4.y < hi) {
      float* p = table + (size_t)d4.y * 3;
      atomic_add_l2(p + 0, a.w);
      atomic_add_l2(p + 1, b.x);
      atomic_add_l2(p + 2, b.y);
    }
    if (d4.z >= lo && d4.z < hi) {
      float* p = table + (size_t)d4.z * 3;
      atomic_add_l2(p + 0, b.z);
      atomic_add_l2(p + 1, b.w);
      atomic_add_l2(p + 2, c.x);
    }
    if (d4.w >= lo && d4.w < hi) {
      float* p = table + (size_t)d4.w * 3;
      atomic_add_l2(p + 0, c.y);
      atomic_add_l2(p + 1, c.z);
      atomic_add_l2(p + 2, c.w);
    }
  } else {
    for (int e = e0; e < n_edges; ++e) {
      int d = tgt[e];
      if (d >= lo && d < hi) {
        float* p = table + (size_t)d * 3;
        atomic_add_l2(p + 0, eattr[(size_t)e * 3 + 0]);
        atomic_add_l2(p + 1, eattr[(size_t)e * 3 + 1]);
        atomic_add_l2(p + 2, eattr[(size_t)e * 3 + 2]);
      }
    }
  }
}

// Fallback (small ws): single-table device-scope atomics (R1 baseline path).
__global__ __launch_bounds__(256) void scatter_dev_kernel(
    const int* __restrict__ tgt, const float* __restrict__ eattr,
    float* __restrict__ agg, int n_edges) {
  int t = blockIdx.x * blockDim.x + threadIdx.x;
  int e0 = t * 4;
  if (e0 >= n_edges) return;
  if (e0 + 4 <= n_edges) {
    int4 d4 = *(const int4*)(tgt + e0);
    const float4* ea = (const float4*)(eattr + (size_t)e0 * 3);
    float4 a = ea[0];
    float4 b = ea[1];
    float4 c = ea[2];
    atomicAdd(&agg[d4.x * 3 + 0], a.x);
    atomicAdd(&agg[d4.x * 3 + 1], a.y);
    atomicAdd(&agg[d4.x * 3 + 2], a.z);
    atomicAdd(&agg[d4.y * 3 + 0], a.w);
    atomicAdd(&agg[d4.y * 3 + 1], b.x);
    atomicAdd(&agg[d4.y * 3 + 2], b.y);
    atomicAdd(&agg[d4.z * 3 + 0], b.z);
    atomicAdd(&agg[d4.z * 3 + 1], b.w);
    atomicAdd(&agg[d4.z * 3 + 2], c.x);
    atomicAdd(&agg[d4.w * 3 + 0], c.y);
    atomicAdd(&agg[d4.w * 3 + 1], c.z);
    atomicAdd(&agg[d4.w * 3 + 2], c.w);
  } else {
    for (int e = e0; e < n_edges; ++e) {
      int d = tgt[e];
      atomicAdd(&agg[d * 3 + 0], eattr[(size_t)e * 3 + 0]);
      atomicAdd(&agg[d * 3 + 1], eattr[(size_t)e * 3 + 1]);
      atomicAdd(&agg[d * 3 + 2], eattr[(size_t)e * 3 + 2]);
    }
  }
}

__global__ __launch_bounds__(256) void mlp_reduce_kernel(
    const float* __restrict__ va,      // [N,2]
    const float* __restrict__ tables,  // [n_tables, N, 3]
    int n_tables, size_t table_stride,
    const float* __restrict__ W1, const float* __restrict__ b1,
    const float* __restrict__ W2, const float* __restrict__ b2,
    const float* __restrict__ W3, const float* __restrict__ b3,
    float* __restrict__ out, int n) {
  int i = blockIdx.x * blockDim.x + threadIdx.x;
  if (i >= n) return;

  float x[5];
  float2 v = ((const float2*)va)[i];
  x[0] = v.x;
  x[1] = v.y;
  float a0 = 0.f, a1 = 0.f, a2 = 0.f;
  for (int t = 0; t < n_tables; ++t) {
    const float* p = tables + (size_t)t * table_stride + (size_t)i * 3;
    a0 += p[0];
    a1 += p[1];
    a2 += p[2];
  }
  x[2] = a0;
  x[3] = a1;
  x[4] = a2;

  float h1[50];
#pragma unroll
  for (int j = 0; j < 50; ++j) {
    float s = b1[j];
#pragma unroll
    for (int k = 0; k < 5; ++k) s = fmaf(W1[j * 5 + k], x[k], s);
    h1[j] = fmaxf(s, 0.0f);
  }

  float h2[20];
  for (int j = 0; j < 20; ++j) {
    float s = b2[j];
#pragma unroll
    for (int k = 0; k < 50; ++k) s = fmaf(W2[j * 50 + k], h1[k], s);
    h2[j] = fmaxf(s, 0.0f);
  }

  float s = b3[0];
#pragma unroll
  for (int k = 0; k < 20; ++k) s = fmaf(W3[k], h2[k], s);
  out[i] = s;
}

extern "C" void kernel_launch(void* const* d_in, const int* in_sizes, int n_in,
                              void* d_out, int out_size, void* d_ws, size_t ws_size,
                              hipStream_t stream) {
  const float* vertex_attr = (const float*)d_in[0];
  const int* edge_index = (const int*)d_in[1];  // [2, E] int32
  const float* edge_attr = (const float*)d_in[2];
  const float* W1 = (const float*)d_in[3];
  const float* b1 = (const float*)d_in[4];
  const float* W2 = (const float*)d_in[5];
  const float* b2 = (const float*)d_in[6];
  const float* W3 = (const float*)d_in[7];
  const float* b3 = (const float*)d_in[8];
  float* out = (float*)d_out;

  const int n_nodes = in_sizes[0] / 2;   // V_DIM = 2
  const int n_edges = in_sizes[2] / 3;   // E_DIM = 3
  const int* tgt = edge_index + n_edges; // row 1 = targets

  const size_t table_stride = (size_t)n_nodes * 3;
  const size_t needed = table_stride * N_XCD * sizeof(float);

  const int sc_threads = (n_edges + 3) / 4;
  const int sc_blocks = (sc_threads + 255) / 256;
  const int mlp_blocks = (n_nodes + 255) / 256;

  if (ws_size >= needed) {
    float* tables = (float*)d_ws;
    hipMemsetAsync(tables, 0, needed, stream);
    const int mid = n_nodes / 2;
    // Pass 0: node slice [0, mid) -> 3 MB/XCD table slice, L2-resident.
    scatter_xcd_kernel<<<sc_blocks, 256, 0, stream>>>(
        tgt, edge_attr, tables, table_stride, n_edges, 0, mid);
    // Pass 1: node slice [mid, n_nodes).
    scatter_xcd_kernel<<<sc_blocks, 256, 0, stream>>>(
        tgt, edge_attr, tables, table_stride, n_edges, mid, n_nodes);
    mlp_reduce_kernel<<<mlp_blocks, 256, 0, stream>>>(
        vertex_attr, tables, N_XCD, table_stride, W1, b1, W2, b2, W3, b3, out,
        n_nodes);
  } else {
    float* agg = (float*)d_ws;
    hipMemsetAsync(agg, 0, table_stride * sizeof(float), stream);
    scatter_dev_kernel<<<sc_blocks, 256, 0, stream>>>(tgt, edge_attr, agg,
                                                      n_edges);
    mlp_reduce_kernel<<<mlp_blocks, 256, 0, stream>>>(
        vertex_attr, agg, 1, table_stride, W1, b1, W2, b2, W3, b3, out,
        n_nodes);
  }
}

// Round 4
// 943.400 us; speedup vs baseline: 2.8019x; 2.8019x over previous
//
#include <hip/hip_runtime.h>
#include <stdint.h>

// N_NODES=500000, N_EDGES=16000000, V_DIM=2, E_DIM=3. MLP: 5->50->20->1.
//
// R1/R3 lesson: per-edge global fp32 atomics (any scope, any sc bits) cost a
// 32 B memory-side transaction each, rate-limited at ~20.5 G ops/s -> 48M
// atomics = 2.3 ms. So: counting-sort edges into 1024-node buckets (16 B
// records), then per-bucket LDS aggregation (LDS atomics are ~free), then
// coalesced table write + MLP. Only ~240K global int atomics remain.
// Edge range is chunked if ws_size can't hold all 256 MB of records.

#define NB_MAX 512   // max buckets -> supports n_nodes <= 524288
#define BSHIFT 10    // 1024 nodes per bucket
#define BNODES 1024
#define EPB 32768    // edges per block in hist/bin kernels
#define THREADS 256

typedef float vf4 __attribute__((ext_vector_type(4)));

// ---------------- K0: per-chunk global histogram of bucket ids ----------------
__global__ __launch_bounds__(THREADS) void hist_kernel(
    const int* __restrict__ tgt, int e_lo, int e_hi, int* __restrict__ g_hist) {
  __shared__ int h[NB_MAX];
  for (int i = threadIdx.x; i < NB_MAX; i += THREADS) h[i] = 0;
  __syncthreads();
  int base = e_lo + blockIdx.x * EPB;
  int end = min(base + EPB, e_hi);
  for (int e = base + (int)threadIdx.x; e < end; e += THREADS)
    atomicAdd(&h[tgt[e] >> BSHIFT], 1);
  __syncthreads();
  for (int i = threadIdx.x; i < NB_MAX; i += THREADS) {
    int v = h[i];
    if (v) atomicAdd(&g_hist[i], v);
  }
}

// ---------------- scan: exclusive prefix sum over NB_MAX buckets --------------
__global__ __launch_bounds__(NB_MAX) void scan_kernel(
    const int* __restrict__ g_hist, int* __restrict__ g_base,
    int* __restrict__ g_cursor) {
  __shared__ int s[NB_MAX];
  int tid = threadIdx.x;
  int h0 = g_hist[tid];
  s[tid] = h0;
  __syncthreads();
  for (int off = 1; off < NB_MAX; off <<= 1) {
    int v = (tid >= off) ? s[tid - off] : 0;
    __syncthreads();
    s[tid] += v;
    __syncthreads();
  }
  int excl = s[tid] - h0;  // exclusive prefix
  g_base[tid] = excl;
  g_cursor[tid] = excl;
}

// ---------------- K1: scatter edges into bucket-sorted record array -----------
// Two-phase per workgroup: LDS histogram -> one global atomicAdd per
// (wg,bucket) to reserve a contiguous span -> scatter records.
__global__ __launch_bounds__(THREADS) void bin_kernel(
    const int* __restrict__ tgt, const float* __restrict__ eattr,
    int e_lo, int e_hi, int* __restrict__ g_cursor, vf4* __restrict__ records) {
  __shared__ int h[NB_MAX];      // counts, then per-bucket running cursor
  __shared__ int wbase[NB_MAX];  // this wg's reserved base per bucket
  for (int i = threadIdx.x; i < NB_MAX; i += THREADS) h[i] = 0;
  __syncthreads();
  int base = e_lo + blockIdx.x * EPB;
  int end = min(base + EPB, e_hi);
  for (int e = base + (int)threadIdx.x; e < end; e += THREADS)
    atomicAdd(&h[tgt[e] >> BSHIFT], 1);
  __syncthreads();
  for (int i = threadIdx.x; i < NB_MAX; i += THREADS) {
    int c = h[i];
    wbase[i] = c ? atomicAdd(&g_cursor[i], c) : 0;
    h[i] = 0;  // reuse as local cursor
  }
  __syncthreads();
  for (int e = base + (int)threadIdx.x; e < end; e += THREADS) {
    int t = tgt[e];
    int b = t >> BSHIFT;
    int slot = wbase[b] + atomicAdd(&h[b], 1);
    const float* ep = eattr + (size_t)e * 3;
    vf4 r;
    r.x = ep[0];
    r.y = ep[1];
    r.z = ep[2];
    r.w = __int_as_float(t);
    records[slot] = r;
  }
}

// ---------------- K2: per-bucket LDS aggregation -> table ---------------------
__global__ __launch_bounds__(THREADS) void agg_kernel(
    const vf4* __restrict__ records, const int* __restrict__ g_base,
    const int* __restrict__ g_hist, float* __restrict__ table, int n_nodes,
    int first_chunk) {
  __shared__ float acc[BNODES * 3];  // 12 KB
  for (int i = threadIdx.x; i < BNODES * 3; i += THREADS) acc[i] = 0.f;
  __syncthreads();
  int b = blockIdx.x;
  int cnt = g_hist[b];
  int rbase = g_base[b];
  int n0 = b << BSHIFT;
  for (int i = threadIdx.x; i < cnt; i += THREADS) {
    vf4 r = records[rbase + i];  // coalesced 16 B/lane
    int local = __float_as_int(r.w) - n0;
    atomicAdd(&acc[local * 3 + 0], r.x);
    atomicAdd(&acc[local * 3 + 1], r.y);
    atomicAdd(&acc[local * 3 + 2], r.z);
  }
  __syncthreads();
  int nn = min(BNODES, n_nodes - n0);
  float* trow = table + (size_t)n0 * 3;
  if (first_chunk) {
    for (int i = threadIdx.x; i < nn * 3; i += THREADS) trow[i] = acc[i];
  } else {
    for (int i = threadIdx.x; i < nn * 3; i += THREADS) trow[i] += acc[i];
  }
}

// ---------------- fallback scatter (tiny ws only) -----------------------------
__global__ __launch_bounds__(THREADS) void scatter_dev_kernel(
    const int* __restrict__ tgt, const float* __restrict__ eattr,
    float* __restrict__ agg, int n_edges) {
  int e = blockIdx.x * blockDim.x + threadIdx.x;
  if (e >= n_edges) return;
  int d = tgt[e];
  atomicAdd(&agg[d * 3 + 0], eattr[(size_t)e * 3 + 0]);
  atomicAdd(&agg[d * 3 + 1], eattr[(size_t)e * 3 + 1]);
  atomicAdd(&agg[d * 3 + 2], eattr[(size_t)e * 3 + 2]);
}

// ---------------- K3: per-node MLP --------------------------------------------
__global__ __launch_bounds__(THREADS) void mlp_kernel(
    const float* __restrict__ va,     // [N,2]
    const float* __restrict__ table,  // [N,3]
    const float* __restrict__ W1, const float* __restrict__ b1,
    const float* __restrict__ W2, const float* __restrict__ b2,
    const float* __restrict__ W3, const float* __restrict__ b3,
    float* __restrict__ out, int n) {
  int i = blockIdx.x * blockDim.x + threadIdx.x;
  if (i >= n) return;

  float x[5];
  float2 v = ((const float2*)va)[i];
  x[0] = v.x;
  x[1] = v.y;
  x[2] = table[(size_t)i * 3 + 0];
  x[3] = table[(size_t)i * 3 + 1];
  x[4] = table[(size_t)i * 3 + 2];

  float h1[50];
#pragma unroll
  for (int j = 0; j < 50; ++j) {
    float s = b1[j];
#pragma unroll
    for (int k = 0; k < 5; ++k) s = fmaf(W1[j * 5 + k], x[k], s);
    h1[j] = fmaxf(s, 0.0f);
  }

  float h2[20];
  for (int j = 0; j < 20; ++j) {
    float s = b2[j];
#pragma unroll
    for (int k = 0; k < 50; ++k) s = fmaf(W2[j * 50 + k], h1[k], s);
    h2[j] = fmaxf(s, 0.0f);
  }

  float s = b3[0];
#pragma unroll
  for (int k = 0; k < 20; ++k) s = fmaf(W3[k], h2[k], s);
  out[i] = s;
}

extern "C" void kernel_launch(void* const* d_in, const int* in_sizes, int n_in,
                              void* d_out, int out_size, void* d_ws, size_t ws_size,
                              hipStream_t stream) {
  const float* vertex_attr = (const float*)d_in[0];
  const int* edge_index = (const int*)d_in[1];  // [2, E] int32
  const float* edge_attr = (const float*)d_in[2];
  const float* W1 = (const float*)d_in[3];
  const float* b1 = (const float*)d_in[4];
  const float* W2 = (const float*)d_in[5];
  const float* b2 = (const float*)d_in[6];
  const float* W3 = (const float*)d_in[7];
  const float* b3 = (const float*)d_in[8];
  float* out = (float*)d_out;

  const int n_nodes = in_sizes[0] / 2;   // V_DIM = 2
  const int n_edges = in_sizes[2] / 3;   // E_DIM = 3
  const int* tgt = edge_index + n_edges; // row 1 = targets

  const int NB = (n_nodes + BNODES - 1) >> BSHIFT;  // runtime bucket count

  // ws layout: [table n_nodes*3 f32][g_hist][g_base][g_cursor][records ...]
  char* ws = (char*)d_ws;
  const size_t table_bytes = (size_t)n_nodes * 3 * sizeof(float);
  float* table = (float*)ws;
  size_t off = (table_bytes + 255) & ~(size_t)255;
  int* g_hist = (int*)(ws + off);
  int* g_base = g_hist + NB_MAX;
  int* g_cursor = g_base + NB_MAX;
  size_t rec_off = (off + 3 * NB_MAX * sizeof(int) + 255) & ~(size_t)255;
  const size_t rec_space =
      (ws_size > rec_off) ? (ws_size - rec_off) : 0;
  const size_t cap_edges = rec_space / sizeof(vf4);
  vf4* records = (vf4*)(ws + rec_off);

  const int mlp_blocks = (n_nodes + THREADS - 1) / THREADS;

  if (NB <= NB_MAX && cap_edges >= (size_t)EPB) {
    // nchunk: smallest chunking whose records fit in ws
    int nchunk = (int)((n_edges + cap_edges - 1) / cap_edges);
    if (nchunk < 1) nchunk = 1;
    const int ce = (n_edges + nchunk - 1) / nchunk;  // edges per chunk
    for (int c = 0; c < nchunk; ++c) {
      const int e_lo = c * ce;
      const int e_hi = min(n_edges, e_lo + ce);
      const int nblk = (e_hi - e_lo + EPB - 1) / EPB;
      hipMemsetAsync(g_hist, 0, NB_MAX * sizeof(int), stream);
      hist_kernel<<<nblk, THREADS, 0, stream>>>(tgt, e_lo, e_hi, g_hist);
      scan_kernel<<<1, NB_MAX, 0, stream>>>(g_hist, g_base, g_cursor);
      bin_kernel<<<nblk, THREADS, 0, stream>>>(tgt, edge_attr, e_lo, e_hi,
                                               g_cursor, records);
      agg_kernel<<<NB, THREADS, 0, stream>>>(records, g_base, g_hist, table,
                                             n_nodes, c == 0 ? 1 : 0);
    }
  } else {
    // pathological ws: fall back to direct device atomics
    hipMemsetAsync(table, 0, table_bytes, stream);
    const int nblk = (n_edges + THREADS - 1) / THREADS;
    scatter_dev_kernel<<<nblk, THREADS, 0, stream>>>(tgt, edge_attr, table,
                                                     n_edges);
  }

  mlp_kernel<<<mlp_blocks, THREADS, 0, stream>>>(
      vertex_attr, table, W1, b1, W2, b2, W3, b3, out, n_nodes);
}